// Round 2
// baseline (501.271 us; speedup 1.0000x reference)
//
#include <hip/hip_runtime.h>
#include <cstdint>

#define NN 1024
#define BB 32
#define LL 128
#define DE 16
#define HH 4
#define K1 4     // K+1 Chebyshev terms
#define BD 512   // BB*DE columns in the Clenshaw matmuls

// ---------------------------------------------------------------- Q/K projections
__global__ __launch_bounds__(256) void qk_kernel(
    const float* __restrict__ psi_emb, const float* __restrict__ W_q,
    const float* __restrict__ W_k, float* __restrict__ Qbuf, float* __restrict__ Kbuf)
{
    const int idx = blockIdx.x * 256 + threadIdx.x;   // N*H*DE = 65536
    const int n = idx >> 6;
    const int hm = idx & 63;
    const float* e = psi_emb + n * DE;
    float q = 0.f, k = 0.f;
#pragma unroll
    for (int d = 0; d < DE; d++) {
        const float ev = e[d];
        q += ev * W_q[d * 64 + hm];
        k += ev * W_k[d * 64 + hm];
    }
    Qbuf[idx] = q;
    Kbuf[idx] = k;
}

// ---------------------------------------------------------------- blended adjacency
__global__ __launch_bounds__(256) void adj_kernel(
    const float* __restrict__ psi_emb, const float* __restrict__ psi_p,
    const float* __restrict__ alpha_p, const float* __restrict__ Qbuf,
    const float* __restrict__ Kbuf, float* __restrict__ A_eff)
{
    __shared__ float base_row[NN];
    __shared__ float attn_row[HH][NN];
    __shared__ float e_i[DE];
    __shared__ float Qi[64];
    __shared__ float red[256];
    __shared__ float sums[5];

    const int i = blockIdx.x;
    const int tid = threadIdx.x;
    if (tid < DE) e_i[tid] = psi_emb[i * DE + tid];
    if (tid >= 64 && tid < 128) Qi[tid - 64] = Qbuf[i * 64 + (tid - 64)];
    __syncthreads();

    const float psi = psi_p[0];
    float sb = 0.f, sa[HH] = {0.f, 0.f, 0.f, 0.f};
    for (int j = tid; j < NN; j += 256) {
        const float* ej = psi_emb + j * DE;
        float d2 = 0.f;
#pragma unroll
        for (int d = 0; d < DE; d++) { const float t = e_i[d] - ej[d]; d2 += t * t; }
        const float bnum = expf(expf(-psi * d2));
        base_row[j] = bnum;
        sb += bnum;
        const float* kj = Kbuf + j * 64;
#pragma unroll
        for (int h = 0; h < HH; h++) {
            float dot = 0.f;
#pragma unroll
            for (int m = 0; m < DE; m++) dot += Qi[h * DE + m] * kj[h * DE + m];
            const float an = expf(dot * 0.25f);
            attn_row[h][j] = an;
            sa[h] += an;
        }
    }
    float vals[5] = {sb, sa[0], sa[1], sa[2], sa[3]};
    for (int q = 0; q < 5; q++) {
        red[tid] = vals[q];
        __syncthreads();
        for (int s = 128; s > 0; s >>= 1) {
            if (tid < s) red[tid] += red[tid + s];
            __syncthreads();
        }
        if (tid == 0) sums[q] = red[0];
        __syncthreads();
    }
    const float alpha = 1.f / (1.f + expf(-alpha_p[0]));
    const float ib = alpha / sums[0];
    float ia[HH];
#pragma unroll
    for (int h = 0; h < HH; h++) ia[h] = (1.f - alpha) / sums[1 + h];
    for (int j = tid; j < NN; j += 256) {
        const float bn = base_row[j] * ib;
#pragma unroll
        for (int h = 0; h < HH; h++)
            A_eff[(size_t)(h * NN + i) * NN + j] = bn + attn_row[h][j] * ia[h];
    }
}

// ---------------------------------------------------------------- F_w transpose
// Wt[l][c] with c = (h*K1+k)*16 + d  = F_w[h][d][k][l]
__global__ __launch_bounds__(256) void wt_kernel(
    const float* __restrict__ F_w, float* __restrict__ Wt)
{
    const int idx = blockIdx.x * 256 + threadIdx.x;  // 128*256
    const int l = idx >> 8;
    const int c = idx & 255;
    const int h = c >> 6, kc = (c >> 4) & 3, d = c & 15;
    Wt[idx] = F_w[((h * DE + d) * K1 + kc) * LL + l];
}

// ---------------------------------------------------------------- G stage as GEMM
// Per b: X_b (1024x128) @ Wt (128x256) -> scattered into G[hk][m][b*16+d].
// 128x128 tile, 256 threads, 8x8 micro as 2x2 blocks of 4x4, double-buffered LDS.
__global__ __launch_bounds__(256, 2) void g_gemm(
    const float* __restrict__ x, const float* __restrict__ Wt, float* __restrict__ G)
{
    const int b  = blockIdx.z;
    const int m0 = blockIdx.y * 128;
    const int c0 = blockIdx.x * 128;
    const float* Xb = x + (size_t)b * NN * LL;

    __shared__ float Xs[2][16][132];   // [k][row], padded
    __shared__ float Ws[2][16][132];   // [k][col], padded

    const int tid = threadIdx.x;
    const int tx = tid & 15, ty = tid >> 4;

    const int arow = tid >> 1;             // 0..127
    const int ak0  = (tid & 1) * 8;        // 0 or 8
    const int wc   = (tid & 31) * 4;       // 0..124
    const int wr0  = tid >> 5;             // 0..7 (second load at +8)

    float4 pa0, pa1, pb0, pb1;
    pa0 = *(const float4*)(Xb + (size_t)(m0 + arow) * LL + ak0);
    pa1 = *(const float4*)(Xb + (size_t)(m0 + arow) * LL + ak0 + 4);
    pb0 = *(const float4*)(Wt + (size_t)wr0 * 256 + c0 + wc);
    pb1 = *(const float4*)(Wt + (size_t)(wr0 + 8) * 256 + c0 + wc);

    Xs[0][ak0 + 0][arow] = pa0.x; Xs[0][ak0 + 1][arow] = pa0.y;
    Xs[0][ak0 + 2][arow] = pa0.z; Xs[0][ak0 + 3][arow] = pa0.w;
    Xs[0][ak0 + 4][arow] = pa1.x; Xs[0][ak0 + 5][arow] = pa1.y;
    Xs[0][ak0 + 6][arow] = pa1.z; Xs[0][ak0 + 7][arow] = pa1.w;
    *(float4*)&Ws[0][wr0][wc]     = pb0;
    *(float4*)&Ws[0][wr0 + 8][wc] = pb1;
    __syncthreads();

    float acc[8][8];
#pragma unroll
    for (int i = 0; i < 8; i++)
#pragma unroll
        for (int j = 0; j < 8; j++) acc[i][j] = 0.f;

    int buf = 0;
    for (int k0 = 16; k0 <= LL; k0 += 16) {
        if (k0 < LL) {
            pa0 = *(const float4*)(Xb + (size_t)(m0 + arow) * LL + k0 + ak0);
            pa1 = *(const float4*)(Xb + (size_t)(m0 + arow) * LL + k0 + ak0 + 4);
            pb0 = *(const float4*)(Wt + (size_t)(k0 + wr0) * 256 + c0 + wc);
            pb1 = *(const float4*)(Wt + (size_t)(k0 + wr0 + 8) * 256 + c0 + wc);
        }
#pragma unroll
        for (int kk = 0; kk < 16; kk++) {
            const float4 a0 = *(const float4*)&Xs[buf][kk][ty * 4];
            const float4 a1 = *(const float4*)&Xs[buf][kk][64 + ty * 4];
            const float4 b0 = *(const float4*)&Ws[buf][kk][tx * 4];
            const float4 b1 = *(const float4*)&Ws[buf][kk][64 + tx * 4];
            const float av[8] = {a0.x, a0.y, a0.z, a0.w, a1.x, a1.y, a1.z, a1.w};
            const float bv[8] = {b0.x, b0.y, b0.z, b0.w, b1.x, b1.y, b1.z, b1.w};
#pragma unroll
            for (int i = 0; i < 8; i++)
#pragma unroll
                for (int j = 0; j < 8; j++) acc[i][j] += av[i] * bv[j];
        }
        if (k0 < LL) {
            const int nb = buf ^ 1;
            Xs[nb][ak0 + 0][arow] = pa0.x; Xs[nb][ak0 + 1][arow] = pa0.y;
            Xs[nb][ak0 + 2][arow] = pa0.z; Xs[nb][ak0 + 3][arow] = pa0.w;
            Xs[nb][ak0 + 4][arow] = pa1.x; Xs[nb][ak0 + 5][arow] = pa1.y;
            Xs[nb][ak0 + 6][arow] = pa1.z; Xs[nb][ak0 + 7][arow] = pa1.w;
            *(float4*)&Ws[nb][wr0][wc]     = pb0;
            *(float4*)&Ws[nb][wr0 + 8][wc] = pb1;
            __syncthreads();
            buf = nb;
        }
    }

    const size_t NS = (size_t)NN * BD;
#pragma unroll
    for (int rh = 0; rh < 2; rh++)
#pragma unroll
        for (int r = 0; r < 4; r++) {
            const int row = m0 + rh * 64 + ty * 4 + r;
#pragma unroll
            for (int ch = 0; ch < 2; ch++) {
                const int gc = c0 + ch * 64 + tx * 4;    // global col 0..255
                const int hk = gc >> 4, d0 = gc & 15;
                float4 o;
                o.x = acc[rh * 4 + r][ch * 4 + 0];
                o.y = acc[rh * 4 + r][ch * 4 + 1];
                o.z = acc[rh * 4 + r][ch * 4 + 2];
                o.w = acc[rh * 4 + r][ch * 4 + 3];
                *(float4*)(G + (size_t)hk * NS + (size_t)row * BD + b * DE + d0) = o;
            }
        }
}

// ---------------------------------------------------------------- Clenshaw GEMM
// O = scale*(A @ B) + pc*P + qc*Q per head. A (N,N), B/P/Q/O (N,512) row-major.
// 128x64 tile, 256 threads, 8x4 micro as 2 blocks of 4x4 rows, double-buffered LDS.
__global__ __launch_bounds__(256) void gemm_ep(
    const float* __restrict__ Abase,
    const float* __restrict__ Bbase, size_t sB,
    const float* __restrict__ Pbase, size_t sP,
    const float* __restrict__ Qbase, size_t sQ,
    float* __restrict__ Obase, size_t sO,
    float scale, float pc, float qc)
{
    const int h = blockIdx.z;
    const float* A  = Abase + (size_t)h * NN * NN;
    const float* Bm = Bbase + (size_t)h * sB;
    const float* P  = Pbase + (size_t)h * sP;
    const float* Q  = Qbase + (size_t)h * sQ;
    float* O        = Obase + (size_t)h * sO;

    const int c0 = blockIdx.x * 64;
    const int n0 = blockIdx.y * 128;

    __shared__ float As[2][16][132];   // [k][row], padded
    __shared__ float Bs[2][16][68];    // [k][col], padded

    const int tid = threadIdx.x;
    const int tx = tid & 15, ty = tid >> 4;

    const int arow = tid >> 1;          // 0..127
    const int ak0  = (tid & 1) * 8;     // 0 or 8
    const int brow = tid >> 4;          // 0..15
    const int bc4  = (tid & 15) * 4;    // 0..60

    float4 pa0, pa1, pbv;
    pa0 = *(const float4*)(A + (size_t)(n0 + arow) * NN + ak0);
    pa1 = *(const float4*)(A + (size_t)(n0 + arow) * NN + ak0 + 4);
    pbv = *(const float4*)(Bm + (size_t)brow * BD + c0 + bc4);

    As[0][ak0 + 0][arow] = pa0.x; As[0][ak0 + 1][arow] = pa0.y;
    As[0][ak0 + 2][arow] = pa0.z; As[0][ak0 + 3][arow] = pa0.w;
    As[0][ak0 + 4][arow] = pa1.x; As[0][ak0 + 5][arow] = pa1.y;
    As[0][ak0 + 6][arow] = pa1.z; As[0][ak0 + 7][arow] = pa1.w;
    *(float4*)&Bs[0][brow][bc4] = pbv;
    __syncthreads();

    float acc[8][4];
#pragma unroll
    for (int i = 0; i < 8; i++)
#pragma unroll
        for (int j = 0; j < 4; j++) acc[i][j] = 0.f;

    int buf = 0;
    for (int k0 = 16; k0 <= NN; k0 += 16) {
        if (k0 < NN) {
            pa0 = *(const float4*)(A + (size_t)(n0 + arow) * NN + k0 + ak0);
            pa1 = *(const float4*)(A + (size_t)(n0 + arow) * NN + k0 + ak0 + 4);
            pbv = *(const float4*)(Bm + (size_t)(k0 + brow) * BD + c0 + bc4);
        }
#pragma unroll
        for (int kk = 0; kk < 16; kk++) {
            const float4 a0 = *(const float4*)&As[buf][kk][ty * 4];
            const float4 a1 = *(const float4*)&As[buf][kk][64 + ty * 4];
            const float4 b0 = *(const float4*)&Bs[buf][kk][tx * 4];
            const float av[8] = {a0.x, a0.y, a0.z, a0.w, a1.x, a1.y, a1.z, a1.w};
            const float bv[4] = {b0.x, b0.y, b0.z, b0.w};
#pragma unroll
            for (int i = 0; i < 8; i++)
#pragma unroll
                for (int j = 0; j < 4; j++) acc[i][j] += av[i] * bv[j];
        }
        if (k0 < NN) {
            const int nb = buf ^ 1;
            As[nb][ak0 + 0][arow] = pa0.x; As[nb][ak0 + 1][arow] = pa0.y;
            As[nb][ak0 + 2][arow] = pa0.z; As[nb][ak0 + 3][arow] = pa0.w;
            As[nb][ak0 + 4][arow] = pa1.x; As[nb][ak0 + 5][arow] = pa1.y;
            As[nb][ak0 + 6][arow] = pa1.z; As[nb][ak0 + 7][arow] = pa1.w;
            *(float4*)&Bs[nb][brow][bc4] = pbv;
            __syncthreads();
            buf = nb;
        }
    }

#pragma unroll
    for (int rh = 0; rh < 2; rh++)
#pragma unroll
        for (int r = 0; r < 4; r++) {
            const size_t row = n0 + rh * 64 + ty * 4 + r;
            const size_t off = row * BD + c0 + tx * 4;
            const float4 p = *(const float4*)(P + off);
            const float4 q = *(const float4*)(Q + off);
            float4 o;
            o.x = scale * acc[rh * 4 + r][0] + pc * p.x + qc * q.x;
            o.y = scale * acc[rh * 4 + r][1] + pc * p.y + qc * q.y;
            o.z = scale * acc[rh * 4 + r][2] + pc * p.z + qc * q.z;
            o.w = scale * acc[rh * 4 + r][3] + pc * p.w + qc * q.w;
            *(float4*)(O + off) = o;
        }
}

// ---------------------------------------------------------------- final contraction
__global__ __launch_bounds__(256) void out_kernel(
    const float* __restrict__ psi_emb, const float* __restrict__ f_b,
    const float* __restrict__ head_mix, const float* __restrict__ S,
    float* __restrict__ out)
{
    const int id = blockIdx.x * 256 + threadIdx.x;  // id = b*N + n
    const int n = id & (NN - 1);
    const int b = id >> 10;
    const float hm0 = head_mix[0], hm1 = head_mix[1], hm2 = head_mix[2], hm3 = head_mix[3];
    const float mx = fmaxf(fmaxf(hm0, hm1), fmaxf(hm2, hm3));
    const float w0 = expf(hm0 - mx), w1 = expf(hm1 - mx), w2 = expf(hm2 - mx), w3 = expf(hm3 - mx);
    const float isum = 1.f / (w0 + w1 + w2 + w3);
    const float mw[4] = {w0 * isum, w1 * isum, w2 * isum, w3 * isum};
    float e[DE];
#pragma unroll
    for (int d = 0; d < DE; d++) e[d] = psi_emb[n * DE + d];
    float total = 0.f;
#pragma unroll
    for (int h = 0; h < HH; h++) {
        const float* sp = S + ((size_t)h * NN + n) * BD + b * DE;
        const float* fb = f_b + h * DE;
        float acc = 0.f;
#pragma unroll
        for (int d = 0; d < DE; d++) acc += e[d] * (sp[d] + fb[d]);
        total += mw[h] * acc;
    }
    out[id] = total;
}

extern "C" void kernel_launch(void* const* d_in, const int* in_sizes, int n_in,
                              void* d_out, int out_size, void* d_ws, size_t ws_size,
                              hipStream_t stream)
{
    const float* x          = (const float*)d_in[0];
    const float* psi_emb    = (const float*)d_in[1];
    const float* psi        = (const float*)d_in[2];
    const float* W_q        = (const float*)d_in[3];
    const float* W_k        = (const float*)d_in[4];
    const float* attn_alpha = (const float*)d_in[5];
    const float* F_w        = (const float*)d_in[6];
    const float* f_b        = (const float*)d_in[7];
    const float* head_mix   = (const float*)d_in[8];
    float* out = (float*)d_out;

    float* ws = (float*)d_ws;
    const size_t NS = (size_t)NN * BD;            // 524288 floats per (h) slab
    float* Qbuf  = ws;                            // 65536
    float* Kbuf  = Qbuf + (size_t)NN * HH * DE;   // 65536
    float* A_eff = Kbuf + (size_t)NN * HH * DE;   // H*N*N = 4194304
    float* G     = A_eff + (size_t)HH * NN * NN;  // H*K1*N*BD = 8388608
    float* b2    = G + (size_t)HH * K1 * NS;      // H*N*BD
    float* b1    = b2 + (size_t)HH * NS;
    float* Sf    = b1 + (size_t)HH * NS;
    float* Wt    = Sf + (size_t)HH * NS;          // 128*256 = 32768
    const size_t need_bytes = (size_t)((Wt + 32768) - ws) * sizeof(float);
    if (ws_size < need_bytes) return;

    qk_kernel<<<NN * HH * DE / 256, 256, 0, stream>>>(psi_emb, W_q, W_k, Qbuf, Kbuf);
    adj_kernel<<<NN, 256, 0, stream>>>(psi_emb, psi, attn_alpha, Qbuf, Kbuf, A_eff);
    wt_kernel<<<LL * 256 / 256, 256, 0, stream>>>(F_w, Wt);
    {
        const dim3 gg(256 / 128, NN / 128, BB);
        g_gemm<<<gg, 256, 0, stream>>>(x, Wt, G);
    }

    const dim3 gg(BD / 64, NN / 128, HH);
    // Clenshaw: b2 = G2 + 2*A@G3
    gemm_ep<<<gg, 256, 0, stream>>>(A_eff, G + 3 * NS, K1 * NS, G + 2 * NS, K1 * NS,
                                    G + 2 * NS, K1 * NS, b2, NS, 2.f, 1.f, 0.f);
    // b1 = G1 + 2*A@b2 - G3
    gemm_ep<<<gg, 256, 0, stream>>>(A_eff, b2, NS, G + 1 * NS, K1 * NS,
                                    G + 3 * NS, K1 * NS, b1, NS, 2.f, 1.f, -1.f);
    // Sf = G0 + A@b1 - b2
    gemm_ep<<<gg, 256, 0, stream>>>(A_eff, b1, NS, G, K1 * NS,
                                    b2, NS, Sf, NS, 1.f, 1.f, -1.f);

    out_kernel<<<BB * NN / 256, 256, 0, stream>>>(psi_emb, f_b, head_mix, Sf, out);
}

// Round 3
// 462.366 us; speedup vs baseline: 1.0841x; 1.0841x over previous
//
#include <hip/hip_runtime.h>
#include <cstdint>

#define NN 1024
#define BB 32
#define LL 128
#define DE 16
#define HH 4
#define K1 4     // K+1 Chebyshev terms
#define BD 512   // BB*DE columns in the Clenshaw matmuls

// ---------------------------------------------------------------- Q/K projections
__global__ __launch_bounds__(256) void qk_kernel(
    const float* __restrict__ psi_emb, const float* __restrict__ W_q,
    const float* __restrict__ W_k, float* __restrict__ Qbuf, float* __restrict__ Kbuf)
{
    const int idx = blockIdx.x * 256 + threadIdx.x;   // N*H*DE = 65536
    const int n = idx >> 6;
    const int hm = idx & 63;
    const float* e = psi_emb + n * DE;
    float q = 0.f, k = 0.f;
#pragma unroll
    for (int d = 0; d < DE; d++) {
        const float ev = e[d];
        q += ev * W_q[d * 64 + hm];
        k += ev * W_k[d * 64 + hm];
    }
    Qbuf[idx] = q;
    Kbuf[idx] = k;
}

// ---------------------------------------------------------------- blended adjacency
__global__ __launch_bounds__(256) void adj_kernel(
    const float* __restrict__ psi_emb, const float* __restrict__ psi_p,
    const float* __restrict__ alpha_p, const float* __restrict__ Qbuf,
    const float* __restrict__ Kbuf, float* __restrict__ A_eff)
{
    __shared__ float base_row[NN];
    __shared__ float attn_row[HH][NN];
    __shared__ float e_i[DE];
    __shared__ float Qi[64];
    __shared__ float red[256];
    __shared__ float sums[5];

    const int i = blockIdx.x;
    const int tid = threadIdx.x;
    if (tid < DE) e_i[tid] = psi_emb[i * DE + tid];
    if (tid >= 64 && tid < 128) Qi[tid - 64] = Qbuf[i * 64 + (tid - 64)];
    __syncthreads();

    const float psi = psi_p[0];
    float sb = 0.f, sa[HH] = {0.f, 0.f, 0.f, 0.f};
    for (int j = tid; j < NN; j += 256) {
        const float* ej = psi_emb + j * DE;
        float d2 = 0.f;
#pragma unroll
        for (int d = 0; d < DE; d++) { const float t = e_i[d] - ej[d]; d2 += t * t; }
        const float bnum = expf(expf(-psi * d2));
        base_row[j] = bnum;
        sb += bnum;
        const float* kj = Kbuf + j * 64;
#pragma unroll
        for (int h = 0; h < HH; h++) {
            float dot = 0.f;
#pragma unroll
            for (int m = 0; m < DE; m++) dot += Qi[h * DE + m] * kj[h * DE + m];
            const float an = expf(dot * 0.25f);
            attn_row[h][j] = an;
            sa[h] += an;
        }
    }
    float vals[5] = {sb, sa[0], sa[1], sa[2], sa[3]};
    for (int q = 0; q < 5; q++) {
        red[tid] = vals[q];
        __syncthreads();
        for (int s = 128; s > 0; s >>= 1) {
            if (tid < s) red[tid] += red[tid + s];
            __syncthreads();
        }
        if (tid == 0) sums[q] = red[0];
        __syncthreads();
    }
    const float alpha = 1.f / (1.f + expf(-alpha_p[0]));
    const float ib = alpha / sums[0];
    float ia[HH];
#pragma unroll
    for (int h = 0; h < HH; h++) ia[h] = (1.f - alpha) / sums[1 + h];
    for (int j = tid; j < NN; j += 256) {
        const float bn = base_row[j] * ib;
#pragma unroll
        for (int h = 0; h < HH; h++)
            A_eff[(size_t)(h * NN + i) * NN + j] = bn + attn_row[h][j] * ia[h];
    }
}

// ---------------------------------------------------------------- F_w transpose
// Wt[l][c] with c = (h*K1+k)*16 + d  = F_w[h][d][k][l]
__global__ __launch_bounds__(256) void wt_kernel(
    const float* __restrict__ F_w, float* __restrict__ Wt)
{
    const int idx = blockIdx.x * 256 + threadIdx.x;  // 128*256
    const int l = idx >> 8;
    const int c = idx & 255;
    const int h = c >> 6, kc = (c >> 4) & 3, d = c & 15;
    Wt[idx] = F_w[((h * DE + d) * K1 + kc) * LL + l];
}

// ---------------------------------------------------------------- G stage as GEMM
// Per b: X_b (1024x128) @ Wt (128x256) -> Gx[b][m][c], c=(h*K1+k)*16+d, CONTIGUOUS.
// R2 post-mortem: scattering the store into G[hk][m][b*16+d] caused 14x write
// amplification (partial-line RMW across XCDs). Natural-layout store fixes it;
// the Clenshaw GEMM absorbs the interleave on its (L3-cached) B reads instead.
__global__ __launch_bounds__(256, 2) void g_gemm(
    const float* __restrict__ x, const float* __restrict__ Wt, float* __restrict__ Gx)
{
    const int b  = blockIdx.z;
    const int m0 = blockIdx.y * 128;
    const int c0 = blockIdx.x * 128;
    const float* Xb = x + (size_t)b * NN * LL;

    __shared__ float Xs[2][16][132];   // [k][row], padded
    __shared__ float Ws[2][16][132];   // [k][col], padded

    const int tid = threadIdx.x;
    const int tx = tid & 15, ty = tid >> 4;

    const int arow = tid >> 1;             // 0..127
    const int ak0  = (tid & 1) * 8;        // 0 or 8
    const int wc   = (tid & 31) * 4;       // 0..124
    const int wr0  = tid >> 5;             // 0..7 (second load at +8)

    float4 pa0, pa1, pb0, pb1;
    pa0 = *(const float4*)(Xb + (size_t)(m0 + arow) * LL + ak0);
    pa1 = *(const float4*)(Xb + (size_t)(m0 + arow) * LL + ak0 + 4);
    pb0 = *(const float4*)(Wt + (size_t)wr0 * 256 + c0 + wc);
    pb1 = *(const float4*)(Wt + (size_t)(wr0 + 8) * 256 + c0 + wc);

    Xs[0][ak0 + 0][arow] = pa0.x; Xs[0][ak0 + 1][arow] = pa0.y;
    Xs[0][ak0 + 2][arow] = pa0.z; Xs[0][ak0 + 3][arow] = pa0.w;
    Xs[0][ak0 + 4][arow] = pa1.x; Xs[0][ak0 + 5][arow] = pa1.y;
    Xs[0][ak0 + 6][arow] = pa1.z; Xs[0][ak0 + 7][arow] = pa1.w;
    *(float4*)&Ws[0][wr0][wc]     = pb0;
    *(float4*)&Ws[0][wr0 + 8][wc] = pb1;
    __syncthreads();

    float acc[8][8];
#pragma unroll
    for (int i = 0; i < 8; i++)
#pragma unroll
        for (int j = 0; j < 8; j++) acc[i][j] = 0.f;

    int buf = 0;
    for (int k0 = 16; k0 <= LL; k0 += 16) {
        if (k0 < LL) {
            pa0 = *(const float4*)(Xb + (size_t)(m0 + arow) * LL + k0 + ak0);
            pa1 = *(const float4*)(Xb + (size_t)(m0 + arow) * LL + k0 + ak0 + 4);
            pb0 = *(const float4*)(Wt + (size_t)(k0 + wr0) * 256 + c0 + wc);
            pb1 = *(const float4*)(Wt + (size_t)(k0 + wr0 + 8) * 256 + c0 + wc);
        }
#pragma unroll
        for (int kk = 0; kk < 16; kk++) {
            const float4 a0 = *(const float4*)&Xs[buf][kk][ty * 4];
            const float4 a1 = *(const float4*)&Xs[buf][kk][64 + ty * 4];
            const float4 b0 = *(const float4*)&Ws[buf][kk][tx * 4];
            const float4 b1 = *(const float4*)&Ws[buf][kk][64 + tx * 4];
            const float av[8] = {a0.x, a0.y, a0.z, a0.w, a1.x, a1.y, a1.z, a1.w};
            const float bv[8] = {b0.x, b0.y, b0.z, b0.w, b1.x, b1.y, b1.z, b1.w};
#pragma unroll
            for (int i = 0; i < 8; i++)
#pragma unroll
                for (int j = 0; j < 8; j++) acc[i][j] += av[i] * bv[j];
        }
        if (k0 < LL) {
            const int nb = buf ^ 1;
            Xs[nb][ak0 + 0][arow] = pa0.x; Xs[nb][ak0 + 1][arow] = pa0.y;
            Xs[nb][ak0 + 2][arow] = pa0.z; Xs[nb][ak0 + 3][arow] = pa0.w;
            Xs[nb][ak0 + 4][arow] = pa1.x; Xs[nb][ak0 + 5][arow] = pa1.y;
            Xs[nb][ak0 + 6][arow] = pa1.z; Xs[nb][ak0 + 7][arow] = pa1.w;
            *(float4*)&Ws[nb][wr0][wc]     = pb0;
            *(float4*)&Ws[nb][wr0 + 8][wc] = pb1;
            __syncthreads();
            buf = nb;
        }
    }

    float* Gb = Gx + (size_t)b * NN * 256;
#pragma unroll
    for (int rh = 0; rh < 2; rh++)
#pragma unroll
        for (int r = 0; r < 4; r++) {
            const int row = m0 + rh * 64 + ty * 4 + r;
#pragma unroll
            for (int ch = 0; ch < 2; ch++) {
                const int gc = c0 + ch * 64 + tx * 4;
                float4 o;
                o.x = acc[rh * 4 + r][ch * 4 + 0];
                o.y = acc[rh * 4 + r][ch * 4 + 1];
                o.z = acc[rh * 4 + r][ch * 4 + 2];
                o.w = acc[rh * 4 + r][ch * 4 + 3];
                *(float4*)(Gb + (size_t)row * 256 + gc) = o;   // coalesced, full lines
            }
        }
}

// ---------------------------------------------------------------- Clenshaw GEMM
// O = scale*(A @ B) + pc*P + qc*Q per head. A (N,N) row-major fp32.
// B/P/Q addressed via unified map: addr(h,m,c) = base + h*hs + (c>>4)*s1 + m*sr + (c&15)
//   contiguous (N,512) slab: hs=NS, s1=16,     sr=512
//   Gx slab k:  base=Gx+k*16, hs=64, s1=N*256, sr=256
// O contiguous. 64x64 tile, 256 threads, 4x4 micro, double-buffered LDS.
// 512 blocks = 2 blocks/CU = 2 waves/SIMD (R2's 128x64 gave 1 wave/SIMD -> stalls).
__global__ __launch_bounds__(256) void gemm_ep(
    const float* __restrict__ Abase,
    const float* __restrict__ Bp, size_t hsB, size_t s1B, size_t srB,
    const float* __restrict__ Pp, size_t hsP, size_t s1P, size_t srP,
    const float* __restrict__ Qp, size_t hsQ, size_t s1Q, size_t srQ,
    float* __restrict__ Obase, size_t hsO,
    float scale, float pc, float qc)
{
    const int h = blockIdx.z;
    const float* A = Abase + (size_t)h * NN * NN;
    const float* B = Bp + (size_t)h * hsB;
    const float* P = Pp + (size_t)h * hsP;
    const float* Q = Qp + (size_t)h * hsQ;
    float* O       = Obase + (size_t)h * hsO;

    const int c0 = blockIdx.x * 64;
    const int n0 = blockIdx.y * 64;

    __shared__ float As[2][16][68];   // [k][row], padded
    __shared__ float Bs[2][16][68];   // [k][col], padded

    const int tid = threadIdx.x;
    const int tx = tid & 15, ty = tid >> 4;

    const int arow = tid >> 2;          // 0..63
    const int ak   = (tid & 3) * 4;     // 0,4,8,12
    const int brow = tid >> 4;          // 0..15
    const int bc   = (tid & 15) * 4;    // 0..60

    // B column addressing (constant per thread): col = c0 + bc (+0..3 within float4)
    const size_t bcol_off = (size_t)((c0 + bc) >> 4) * s1B + (size_t)((c0 + bc) & 15);

    float4 pa, pb;
    pa = *(const float4*)(A + (size_t)(n0 + arow) * NN + ak);
    pb = *(const float4*)(B + bcol_off + (size_t)brow * srB);

    As[0][ak + 0][arow] = pa.x; As[0][ak + 1][arow] = pa.y;
    As[0][ak + 2][arow] = pa.z; As[0][ak + 3][arow] = pa.w;
    *(float4*)&Bs[0][brow][bc] = pb;
    __syncthreads();

    float acc[4][4];
#pragma unroll
    for (int i = 0; i < 4; i++)
#pragma unroll
        for (int j = 0; j < 4; j++) acc[i][j] = 0.f;

    int buf = 0;
    for (int k0 = 16; k0 <= NN; k0 += 16) {
        if (k0 < NN) {
            pa = *(const float4*)(A + (size_t)(n0 + arow) * NN + k0 + ak);
            pb = *(const float4*)(B + bcol_off + (size_t)(k0 + brow) * srB);
        }
#pragma unroll
        for (int kk = 0; kk < 16; kk++) {
            const float4 a = *(const float4*)&As[buf][kk][ty * 4];
            const float4 b = *(const float4*)&Bs[buf][kk][tx * 4];
            acc[0][0] += a.x * b.x; acc[0][1] += a.x * b.y; acc[0][2] += a.x * b.z; acc[0][3] += a.x * b.w;
            acc[1][0] += a.y * b.x; acc[1][1] += a.y * b.y; acc[1][2] += a.y * b.z; acc[1][3] += a.y * b.w;
            acc[2][0] += a.z * b.x; acc[2][1] += a.z * b.y; acc[2][2] += a.z * b.z; acc[2][3] += a.z * b.w;
            acc[3][0] += a.w * b.x; acc[3][1] += a.w * b.y; acc[3][2] += a.w * b.z; acc[3][3] += a.w * b.w;
        }
        if (k0 < NN) {
            const int nb = buf ^ 1;
            As[nb][ak + 0][arow] = pa.x; As[nb][ak + 1][arow] = pa.y;
            As[nb][ak + 2][arow] = pa.z; As[nb][ak + 3][arow] = pa.w;
            *(float4*)&Bs[nb][brow][bc] = pb;
            __syncthreads();
            buf = nb;
        }
    }

    const size_t pcol_off = (size_t)((c0 + tx * 4) >> 4) * s1P + (size_t)((c0 + tx * 4) & 15);
    const size_t qcol_off = (size_t)((c0 + tx * 4) >> 4) * s1Q + (size_t)((c0 + tx * 4) & 15);
#pragma unroll
    for (int r = 0; r < 4; r++) {
        const size_t row = n0 + ty * 4 + r;
        const float4 p = *(const float4*)(P + pcol_off + row * srP);
        const float4 q = *(const float4*)(Q + qcol_off + row * srQ);
        float4 o;
        o.x = scale * acc[r][0] + pc * p.x + qc * q.x;
        o.y = scale * acc[r][1] + pc * p.y + qc * q.y;
        o.z = scale * acc[r][2] + pc * p.z + qc * q.z;
        o.w = scale * acc[r][3] + pc * p.w + qc * q.w;
        *(float4*)(O + row * BD + c0 + tx * 4) = o;
    }
}

// ---------------------------------------------------------------- final contraction
__global__ __launch_bounds__(256) void out_kernel(
    const float* __restrict__ psi_emb, const float* __restrict__ f_b,
    const float* __restrict__ head_mix, const float* __restrict__ S,
    float* __restrict__ out)
{
    const int id = blockIdx.x * 256 + threadIdx.x;  // id = b*N + n
    const int n = id & (NN - 1);
    const int b = id >> 10;
    const float hm0 = head_mix[0], hm1 = head_mix[1], hm2 = head_mix[2], hm3 = head_mix[3];
    const float mx = fmaxf(fmaxf(hm0, hm1), fmaxf(hm2, hm3));
    const float w0 = expf(hm0 - mx), w1 = expf(hm1 - mx), w2 = expf(hm2 - mx), w3 = expf(hm3 - mx);
    const float isum = 1.f / (w0 + w1 + w2 + w3);
    const float mw[4] = {w0 * isum, w1 * isum, w2 * isum, w3 * isum};
    float e[DE];
#pragma unroll
    for (int d = 0; d < DE; d++) e[d] = psi_emb[n * DE + d];
    float total = 0.f;
#pragma unroll
    for (int h = 0; h < HH; h++) {
        const float* sp = S + ((size_t)h * NN + n) * BD + b * DE;
        const float* fb = f_b + h * DE;
        float acc = 0.f;
#pragma unroll
        for (int d = 0; d < DE; d++) acc += e[d] * (sp[d] + fb[d]);
        total += mw[h] * acc;
    }
    out[id] = total;
}

extern "C" void kernel_launch(void* const* d_in, const int* in_sizes, int n_in,
                              void* d_out, int out_size, void* d_ws, size_t ws_size,
                              hipStream_t stream)
{
    const float* x          = (const float*)d_in[0];
    const float* psi_emb    = (const float*)d_in[1];
    const float* psi        = (const float*)d_in[2];
    const float* W_q        = (const float*)d_in[3];
    const float* W_k        = (const float*)d_in[4];
    const float* attn_alpha = (const float*)d_in[5];
    const float* F_w        = (const float*)d_in[6];
    const float* f_b        = (const float*)d_in[7];
    const float* head_mix   = (const float*)d_in[8];
    float* out = (float*)d_out;

    float* ws = (float*)d_ws;
    const size_t NS = (size_t)NN * BD;            // 524288 floats per head slab
    float* Qbuf  = ws;                            // 65536
    float* Kbuf  = Qbuf + (size_t)NN * HH * DE;   // 65536
    float* A_eff = Kbuf + (size_t)NN * HH * DE;   // H*N*N = 4194304
    float* Gx    = A_eff + (size_t)HH * NN * NN;  // BB*N*256 = 8388608
    float* b2    = Gx + (size_t)BB * NN * 256;    // H*N*BD
    float* b1    = b2 + (size_t)HH * NS;
    float* Sf    = b1 + (size_t)HH * NS;
    float* Wt    = Sf + (size_t)HH * NS;          // 128*256 = 32768
    const size_t need_bytes = (size_t)((Wt + 32768) - ws) * sizeof(float);
    if (ws_size < need_bytes) return;

    qk_kernel<<<NN * HH * DE / 256, 256, 0, stream>>>(psi_emb, W_q, W_k, Qbuf, Kbuf);
    adj_kernel<<<NN, 256, 0, stream>>>(psi_emb, psi, attn_alpha, Qbuf, Kbuf, A_eff);
    wt_kernel<<<LL * 256 / 256, 256, 0, stream>>>(F_w, Wt);
    {
        const dim3 gg(2, NN / 128, BB);
        g_gemm<<<gg, 256, 0, stream>>>(x, Wt, Gx);
    }

    // Gx slab addressing constants
    const size_t GS1 = (size_t)NN * 256;  // per-b stride
    const size_t GSR = 256;               // per-m stride
    const size_t GHS = 64;                // per-h stride (h*K1*16)
    const float* G0 = Gx + 0 * DE;
    const float* G1 = Gx + 1 * DE;
    const float* G2 = Gx + 2 * DE;
    const float* G3 = Gx + 3 * DE;

    const dim3 gg(BD / 64, NN / 64, HH);
    // b2 = G2 + 2*A@G3
    gemm_ep<<<gg, 256, 0, stream>>>(A_eff,
                                    G3, GHS, GS1, GSR,
                                    G2, GHS, GS1, GSR,
                                    G2, GHS, GS1, GSR,
                                    b2, NS, 2.f, 1.f, 0.f);
    // b1 = G1 + 2*A@b2 - G3
    gemm_ep<<<gg, 256, 0, stream>>>(A_eff,
                                    b2, NS, 16, BD,
                                    G1, GHS, GS1, GSR,
                                    G3, GHS, GS1, GSR,
                                    b1, NS, 2.f, 1.f, -1.f);
    // Sf = G0 + A@b1 - b2
    gemm_ep<<<gg, 256, 0, stream>>>(A_eff,
                                    b1, NS, 16, BD,
                                    G0, GHS, GS1, GSR,
                                    b2, NS, 16, BD,
                                    Sf, NS, 1.f, 1.f, -1.f);

    out_kernel<<<BB * NN / 256, 256, 0, stream>>>(psi_emb, f_b, head_mix, Sf, out);
}

// Round 4
// 208.776 us; speedup vs baseline: 2.4010x; 2.2147x over previous
//
#include <hip/hip_runtime.h>
#include <cstdint>

#define NN 1024
#define BB 32
#define LL 128
#define DE 16
#define HH 4
#define K1 4
#define BD 512
#define NS 524288   // NN*BD, floats per head slab

using bf16x8 = __attribute__((ext_vector_type(8))) short;
using f32x4  = __attribute__((ext_vector_type(4))) float;

__device__ inline unsigned short f2bf(float f) {
    unsigned u = __builtin_bit_cast(unsigned, f);
    u += 0x7FFFu + ((u >> 16) & 1u);          // round-to-nearest-even
    return (unsigned short)(u >> 16);
}

// ---------------------------------------------------------------- Q/K projections
__global__ __launch_bounds__(256) void qk_kernel(
    const float* __restrict__ psi_emb, const float* __restrict__ W_q,
    const float* __restrict__ W_k, float* __restrict__ Qbuf, float* __restrict__ Kbuf)
{
    const int idx = blockIdx.x * 256 + threadIdx.x;   // N*H*DE = 65536
    const int n = idx >> 6;
    const int hm = idx & 63;
    const float* e = psi_emb + n * DE;
    float q = 0.f, k = 0.f;
#pragma unroll
    for (int d = 0; d < DE; d++) {
        const float ev = e[d];
        q += ev * W_q[d * 64 + hm];
        k += ev * W_k[d * 64 + hm];
    }
    Qbuf[idx] = q;
    Kbuf[idx] = k;
}

// ---------------------------------------------------------------- blended adjacency -> At (bf16, fragment-tiled)
// At element (h, i, j) stored at h*1048576 + (j>>3)*8192 + i*8 + (j&7)
__global__ __launch_bounds__(256) void adj_kernel(
    const float* __restrict__ psi_emb, const float* __restrict__ psi_p,
    const float* __restrict__ alpha_p, const float* __restrict__ Qbuf,
    const float* __restrict__ Kbuf, short* __restrict__ At)
{
    __shared__ float base_row[NN];
    __shared__ float attn_row[HH][NN];
    __shared__ float e_i[DE];
    __shared__ float Qi[64];
    __shared__ float red[256];
    __shared__ float sums[5];

    const int i = blockIdx.x;
    const int tid = threadIdx.x;
    if (tid < DE) e_i[tid] = psi_emb[i * DE + tid];
    if (tid >= 64 && tid < 128) Qi[tid - 64] = Qbuf[i * 64 + (tid - 64)];
    __syncthreads();

    const float psi = psi_p[0];
    float sb = 0.f, sa[HH] = {0.f, 0.f, 0.f, 0.f};
    for (int j = tid; j < NN; j += 256) {
        const float* ej = psi_emb + j * DE;
        float d2 = 0.f;
#pragma unroll
        for (int d = 0; d < DE; d++) { const float t = e_i[d] - ej[d]; d2 += t * t; }
        const float bnum = expf(expf(-psi * d2));
        base_row[j] = bnum;
        sb += bnum;
        const float* kj = Kbuf + j * 64;
#pragma unroll
        for (int h = 0; h < HH; h++) {
            float dot = 0.f;
#pragma unroll
            for (int m = 0; m < DE; m++) dot += Qi[h * DE + m] * kj[h * DE + m];
            const float an = expf(dot * 0.25f);
            attn_row[h][j] = an;
            sa[h] += an;
        }
    }
    float vals[5] = {sb, sa[0], sa[1], sa[2], sa[3]};
    for (int qq = 0; qq < 5; qq++) {
        red[tid] = vals[qq];
        __syncthreads();
        for (int s = 128; s > 0; s >>= 1) {
            if (tid < s) red[tid] += red[tid + s];
            __syncthreads();
        }
        if (tid == 0) sums[qq] = red[0];
        __syncthreads();
    }
    const float alpha = 1.f / (1.f + expf(-alpha_p[0]));
    const float ib = alpha / sums[0];
    float ia[HH];
#pragma unroll
    for (int h = 0; h < HH; h++) ia[h] = (1.f - alpha) / sums[1 + h];
    for (int j = tid; j < NN; j += 256) {
        const float bn = base_row[j] * ib;
        const size_t base = (size_t)(j >> 3) * 8192 + (size_t)i * 8 + (j & 7);
#pragma unroll
        for (int h = 0; h < HH; h++)
            At[(size_t)h * 1048576 + base] = (short)f2bf(bn + attn_row[h][j] * ia[h]);
    }
}

// ---------------------------------------------------------------- x -> xt (bf16, A-fragment-tiled per b)
// xt element (b, m, l) at b*131072 + (l>>3)*8192 + m*8 + (l&7)
__global__ __launch_bounds__(256) void xt_cast(
    const float* __restrict__ x, short* __restrict__ xt)
{
    const int m0 = blockIdx.x * 64;
    const int b  = blockIdx.y;
    __shared__ float xs[64][128];
    const int tid = threadIdx.x;
    for (int i = tid; i < 2048; i += 256) {           // 2048 float4s
        const int row = i >> 5, lq = i & 31;
        *(float4*)&xs[row][lq * 4] =
            *(const float4*)(x + ((size_t)(b * NN + m0 + row)) * LL + lq * 4);
    }
    __syncthreads();
    for (int j = tid; j < 1024; j += 256) {
        const int m = j & 63, lc = j >> 6;
        const float* s = &xs[m][lc * 8];
        uint4 pk;
        pk.x = f2bf(s[0]) | ((unsigned)f2bf(s[1]) << 16);
        pk.y = f2bf(s[2]) | ((unsigned)f2bf(s[3]) << 16);
        pk.z = f2bf(s[4]) | ((unsigned)f2bf(s[5]) << 16);
        pk.w = f2bf(s[6]) | ((unsigned)f2bf(s[7]) << 16);
        *(uint4*)(xt + (size_t)b * 131072 + (size_t)lc * 8192 + (size_t)(m0 + m) * 8) = pk;
    }
}

// ---------------------------------------------------------------- F_w -> wtt (bf16, B-fragment-tiled)
// wtt element (l, c) at (l>>3)*2048 + c*8 + (l&7), c = (h*4+k)*16+d
__global__ __launch_bounds__(256) void wtt_cast(
    const float* __restrict__ F_w, short* __restrict__ wtt)
{
    const int j = blockIdx.x * 256 + threadIdx.x;     // 16*256
    const int lc = j >> 8, c = j & 255;
    const int h = c >> 6, k = (c >> 4) & 3, d = c & 15;
    const float* s = F_w + (size_t)((h * DE + d) * K1 + k) * LL + lc * 8;
    uint4 pk;
    pk.x = f2bf(s[0]) | ((unsigned)f2bf(s[1]) << 16);
    pk.y = f2bf(s[2]) | ((unsigned)f2bf(s[3]) << 16);
    pk.z = f2bf(s[4]) | ((unsigned)f2bf(s[5]) << 16);
    pk.w = f2bf(s[6]) | ((unsigned)f2bf(s[7]) << 16);
    *(uint4*)(wtt + (size_t)lc * 2048 + (size_t)c * 8) = pk;
}

// ---------------------------------------------------------------- G stage (MFMA, K=128, registers only)
// Gs slabs fp32: slab id = k*4+h, each (1024 x 512) row-major, col = b*16+d.
// Also writes G3t (bf16 B-fragment-tiled per h) for k==3.
__global__ __launch_bounds__(256) void g_mfma(
    const short* __restrict__ xt, const short* __restrict__ wtt,
    float* __restrict__ Gs, short* __restrict__ g3t)
{
    const int cb = blockIdx.x;           // 0..3  (64 cols)
    const int m0 = blockIdx.y * 64;      // 0..15
    const int bp = blockIdx.z;           // 0..15 (b pair)
    const int tid = threadIdx.x;
    const int wave = tid >> 6, lane = tid & 63;
    const int b  = bp * 2 + (wave >> 1);
    const int wc = wave & 1;
    const int q = lane >> 4, m16 = lane & 15;
    const short* xb = xt + (size_t)b * 131072;

    f32x4 acc[4][2];
#pragma unroll
    for (int mi = 0; mi < 4; mi++)
#pragma unroll
        for (int ni = 0; ni < 2; ni++) acc[mi][ni] = (f32x4){0.f, 0.f, 0.f, 0.f};

#pragma unroll
    for (int ks = 0; ks < 4; ks++) {
        const int kc = ks * 4 + q;
        bf16x8 a[4], bb[2];
#pragma unroll
        for (int mi = 0; mi < 4; mi++)
            a[mi] = *(const bf16x8*)(xb + (size_t)kc * 8192 + (size_t)(m0 + mi * 16 + m16) * 8);
#pragma unroll
        for (int ni = 0; ni < 2; ni++)
            bb[ni] = *(const bf16x8*)(wtt + (size_t)kc * 2048 +
                                      (size_t)(cb * 64 + wc * 32 + ni * 16 + m16) * 8);
#pragma unroll
        for (int mi = 0; mi < 4; mi++)
#pragma unroll
            for (int ni = 0; ni < 2; ni++)
                acc[mi][ni] = __builtin_amdgcn_mfma_f32_16x16x32_bf16(a[mi], bb[ni], acc[mi][ni], 0, 0, 0);
    }

#pragma unroll
    for (int ni = 0; ni < 2; ni++) {
        const int cc = cb * 64 + wc * 32 + ni * 16 + m16;
        const int kk = (cc >> 4) & 3, hh = cc >> 6;
        const int slab = kk * 4 + hh;
        const int col512 = b * 16 + (cc & 15);
        float* gdst = Gs + (size_t)slab * NS;
#pragma unroll
        for (int mi = 0; mi < 4; mi++) {
            const int row0 = m0 + mi * 16 + q * 4;
#pragma unroll
            for (int r = 0; r < 4; r++)
                gdst[(size_t)(row0 + r) * BD + col512] = acc[mi][ni][r];
            if (kk == 3) {
                ushort4 pk;
                pk.x = f2bf(acc[mi][ni][0]); pk.y = f2bf(acc[mi][ni][1]);
                pk.z = f2bf(acc[mi][ni][2]); pk.w = f2bf(acc[mi][ni][3]);
                *(ushort4*)(g3t + (size_t)hh * 524288 +
                            ((size_t)(row0 >> 3) * 512 + col512) * 8 + (row0 & 7)) = pk;
            }
        }
    }
}

// ---------------------------------------------------------------- Clenshaw GEMM (MFMA)
// O = scale*(A@B) + pc*P + qc*Q per head. A from At (tiled bf16), B from Bt (tiled bf16).
// 64x64 tile, 4 waves (2x2 of 32x32), double-buffered LDS, 512 blocks.
__global__ __launch_bounds__(256) void gemm_mf(
    const short* __restrict__ At, const short* __restrict__ Bt,
    const float* __restrict__ P, const float* __restrict__ Q,
    float* __restrict__ O, short* __restrict__ Ot,
    float scale, float pc, float qc, int writeO, int writeOt)
{
    const int h = blockIdx.z;
    const short* Ah = At + (size_t)h * 1048576;
    const short* Bh = Bt + (size_t)h * 524288;
    const float* Ph = P + (size_t)h * NS;
    const float* Qh = Q + (size_t)h * NS;
    float* Oh = O + (size_t)h * NS;
    short* Oth = Ot + (size_t)h * 524288;

    const int c0 = blockIdx.x * 64;
    const int r0 = blockIdx.y * 64;
    const int tid = threadIdx.x;
    const int wave = tid >> 6, lane = tid & 63;
    const int q = lane >> 4, m16 = lane & 15;
    const int wr = wave >> 1, wc = wave & 1;

    __shared__ __align__(16) short As[2][2048];
    __shared__ __align__(16) short Bs[2][2048];

    // stage k0 = 0
    {
        uint4 ra = *(const uint4*)(Ah + ((size_t)wave * 1024 + r0 + lane) * 8);
        uint4 rb = *(const uint4*)(Bh + ((size_t)wave * 512 + c0 + lane) * 8);
        *(uint4*)&As[0][wave * 512 + lane * 8] = ra;
        *(uint4*)&Bs[0][wave * 512 + lane * 8] = rb;
    }
    __syncthreads();

    f32x4 acc[2][2];
#pragma unroll
    for (int mi = 0; mi < 2; mi++)
#pragma unroll
        for (int ni = 0; ni < 2; ni++) acc[mi][ni] = (f32x4){0.f, 0.f, 0.f, 0.f};

    int buf = 0;
    for (int k0 = 32; k0 <= 1024; k0 += 32) {
        uint4 na, nb;
        const bool more = (k0 < 1024);
        if (more) {
            na = *(const uint4*)(Ah + (((size_t)(k0 >> 3) + wave) * 1024 + r0 + lane) * 8);
            nb = *(const uint4*)(Bh + (((size_t)(k0 >> 3) + wave) * 512 + c0 + lane) * 8);
        }
        bf16x8 af0 = *(const bf16x8*)&As[buf][q * 512 + (wr * 32 + m16) * 8];
        bf16x8 af1 = *(const bf16x8*)&As[buf][q * 512 + (wr * 32 + 16 + m16) * 8];
        bf16x8 bf0 = *(const bf16x8*)&Bs[buf][q * 512 + (wc * 32 + m16) * 8];
        bf16x8 bf1 = *(const bf16x8*)&Bs[buf][q * 512 + (wc * 32 + 16 + m16) * 8];
        acc[0][0] = __builtin_amdgcn_mfma_f32_16x16x32_bf16(af0, bf0, acc[0][0], 0, 0, 0);
        acc[0][1] = __builtin_amdgcn_mfma_f32_16x16x32_bf16(af0, bf1, acc[0][1], 0, 0, 0);
        acc[1][0] = __builtin_amdgcn_mfma_f32_16x16x32_bf16(af1, bf0, acc[1][0], 0, 0, 0);
        acc[1][1] = __builtin_amdgcn_mfma_f32_16x16x32_bf16(af1, bf1, acc[1][1], 0, 0, 0);
        if (more) {
            const int nx = buf ^ 1;
            *(uint4*)&As[nx][wave * 512 + lane * 8] = na;
            *(uint4*)&Bs[nx][wave * 512 + lane * 8] = nb;
            __syncthreads();
            buf = nx;
        }
    }

#pragma unroll
    for (int mi = 0; mi < 2; mi++) {
        const int row0 = r0 + wr * 32 + mi * 16 + q * 4;
#pragma unroll
        for (int ni = 0; ni < 2; ni++) {
            const int cc = c0 + wc * 32 + ni * 16 + m16;
            float v[4];
#pragma unroll
            for (int r = 0; r < 4; r++) {
                const size_t off = (size_t)(row0 + r) * BD + cc;
                float t = scale * acc[mi][ni][r] + pc * Ph[off];
                if (qc != 0.f) t += qc * Qh[off];
                v[r] = t;
                if (writeO) Oh[off] = t;
            }
            if (writeOt) {
                ushort4 pk;
                pk.x = f2bf(v[0]); pk.y = f2bf(v[1]); pk.z = f2bf(v[2]); pk.w = f2bf(v[3]);
                *(ushort4*)(Oth + ((size_t)(row0 >> 3) * 512 + cc) * 8 + (row0 & 7)) = pk;
            }
        }
    }
}

// ---------------------------------------------------------------- final contraction
__global__ __launch_bounds__(256) void out_kernel(
    const float* __restrict__ psi_emb, const float* __restrict__ f_b,
    const float* __restrict__ head_mix, const float* __restrict__ S,
    float* __restrict__ out)
{
    const int id = blockIdx.x * 256 + threadIdx.x;  // id = b*N + n
    const int n = id & (NN - 1);
    const int b = id >> 10;
    const float hm0 = head_mix[0], hm1 = head_mix[1], hm2 = head_mix[2], hm3 = head_mix[3];
    const float mx = fmaxf(fmaxf(hm0, hm1), fmaxf(hm2, hm3));
    const float w0 = expf(hm0 - mx), w1 = expf(hm1 - mx), w2 = expf(hm2 - mx), w3 = expf(hm3 - mx);
    const float isum = 1.f / (w0 + w1 + w2 + w3);
    const float mw[4] = {w0 * isum, w1 * isum, w2 * isum, w3 * isum};
    float e[DE];
#pragma unroll
    for (int d = 0; d < DE; d++) e[d] = psi_emb[n * DE + d];
    float total = 0.f;
#pragma unroll
    for (int h = 0; h < HH; h++) {
        const float* sp = S + ((size_t)h * NN + n) * BD + b * DE;
        const float* fb = f_b + h * DE;
        float acc = 0.f;
#pragma unroll
        for (int d = 0; d < DE; d++) acc += e[d] * (sp[d] + fb[d]);
        total += mw[h] * acc;
    }
    out[id] = total;
}

extern "C" void kernel_launch(void* const* d_in, const int* in_sizes, int n_in,
                              void* d_out, int out_size, void* d_ws, size_t ws_size,
                              hipStream_t stream)
{
    const float* x          = (const float*)d_in[0];
    const float* psi_emb    = (const float*)d_in[1];
    const float* psi        = (const float*)d_in[2];
    const float* W_q        = (const float*)d_in[3];
    const float* W_k        = (const float*)d_in[4];
    const float* attn_alpha = (const float*)d_in[5];
    const float* F_w        = (const float*)d_in[6];
    const float* f_b        = (const float*)d_in[7];
    const float* head_mix   = (const float*)d_in[8];
    float* out = (float*)d_out;

    short* At  = (short*)d_ws;                 // 4,194,304 bf16 (A, tiled, per-h 1,048,576)
    short* xt  = At + 4194304;                 // 4,194,304
    short* wtt = xt + 4194304;                 // 32,768
    short* g3t = wtt + 32768;                  // 2,097,152 (per-h 524,288)
    short* b2t = g3t + 2097152;                // 1,048,576... per-h 524,288 -> wait HH*524288 = 2,097,152
    short* b1t = b2t + 2097152;
    float* Gs  = (float*)(b1t + 2097152);      // 16 slabs (k*4+h) x 524,288 fp32
    float* b2  = Gs + 16 * (size_t)NS / 4 * 4; // = Gs + 8,388,608
    float* Qb  = b2 + (size_t)HH * NS;
    float* Kb  = Qb + 65536;
    float* Sf  = Gs + 12 * (size_t)NS;         // alias G3 fp32 block (consumed before gemm3 writes)

    const size_t need_bytes =
        (size_t)(4194304 + 4194304 + 32768 + 2097152 + 2097152 + 2097152) * 2 +
        (size_t)(8388608 + HH * NS + 65536 + 65536) * 4;
    if (ws_size < need_bytes) return;

    qk_kernel<<<NN * HH * DE / 256, 256, 0, stream>>>(psi_emb, W_q, W_k, Qb, Kb);
    adj_kernel<<<NN, 256, 0, stream>>>(psi_emb, psi, attn_alpha, Qb, Kb, At);
    xt_cast<<<dim3(NN / 64, BB), 256, 0, stream>>>(x, xt);
    wtt_cast<<<16, 256, 0, stream>>>(F_w, wtt);
    g_mfma<<<dim3(4, NN / 64, BB / 2), 256, 0, stream>>>(xt, wtt, Gs, g3t);

    const dim3 gg(BD / 64, NN / 64, HH);
    // b2 = G2 + 2*A@G3          (G2 slabs at Gs + 8*NS, h-stride NS)
    gemm_mf<<<gg, 256, 0, stream>>>(At, g3t, Gs + 8 * (size_t)NS, Gs + 8 * (size_t)NS,
                                    b2, b2t, 2.f, 1.f, 0.f, 1, 1);
    // b1 = G1 + 2*A@b2 - G3     (fp32 b1 dead: only bf16 b1t consumed)
    gemm_mf<<<gg, 256, 0, stream>>>(At, b2t, Gs + 4 * (size_t)NS, Gs + 12 * (size_t)NS,
                                    b2 /*unused O*/, b1t, 2.f, 1.f, -1.f, 0, 1);
    // Sf = G0 + A@b1 - b2       (Sf aliases G3 fp32 block, already consumed)
    gemm_mf<<<gg, 256, 0, stream>>>(At, b1t, Gs, b2,
                                    Sf, b1t /*unused Ot*/, 1.f, 1.f, -1.f, 1, 0);

    out_kernel<<<BB * NN / 256, 256, 0, stream>>>(psi_emb, f_b, head_mix, Sf, out);
}